// Round 14
// baseline (65.282 us; speedup 1.0000x reference)
//
#include <hip/hip_runtime.h>
#include <hip/hip_bf16.h>
#include <hip/hip_fp16.h>
#include <hip/hip_fp8.h>

// Self-attention: B=4, N=4096 (64x64 spatial), C=256, D=32.
//   proj_kernel : MFMA GEMM, 64-row blocks (~2.5us). k,q row-major [B*N][32] f16
//                 (q pre-scaled by log2e); v packed fp8 e4m3:
//                 vT4[n/32][lane][16B], lane=(g<<4)|q holds {V[q][4k],V[16+q][4k]}
//                 for both k-tiles of the pair -> ONE 16B V load per iteration.
//   attn_kernel : R10 structure: block = 64 q-rows, 512 threads = 8 waves k-split
//                 (512 k each), swapped-operand MFMA (S^T=K*Q^T, feat^T=V^T*P^T),
//                 1-deep prefetch, defer-max softmax, padded combine, MFMA
//                 Wo-epilogue + residual. V decoded fp8->f16 in-register.

#define BB 4
#define NN 4096
#define CC 256
#define DD 32
#define LOG2E 1.44269504088896340736f
#define THR2 11.0f

typedef _Float16 half_t;
typedef _Float16 half2_t __attribute__((ext_vector_type(2)));
typedef _Float16 half4_t __attribute__((ext_vector_type(4)));
typedef _Float16 half8_t __attribute__((ext_vector_type(8)));
typedef float f32x4 __attribute__((ext_vector_type(4)));

#define MFMA_QK(a, b, c) __builtin_amdgcn_mfma_f32_16x16x32_f16(a, b, c, 0, 0, 0)
#define MFMA_PV(a, b, c) __builtin_amdgcn_mfma_f32_16x16x16f16(a, b, c, 0, 0, 0)

static __device__ inline float fexp2(float x) {
#if __has_builtin(__builtin_amdgcn_exp2f)
    return __builtin_amdgcn_exp2f(x);
#else
    return exp2f(x);
#endif
}

// 4 packed fp8 e4m3 (in a u32) -> 4 f16
static __device__ __forceinline__ half4_t fp8x4_to_half4(unsigned int v) {
    __half2_raw lo = __hip_cvt_fp8x2_to_halfraw2((__hip_fp8x2_storage_t)(v & 0xffffu), __HIP_E4M3);
    __half2_raw hi = __hip_cvt_fp8x2_to_halfraw2((__hip_fp8x2_storage_t)(v >> 16), __HIP_E4M3);
    half4_t r;
    r[0] = *reinterpret_cast<_Float16*>(&lo.x);
    r[1] = *reinterpret_cast<_Float16*>(&lo.y);
    r[2] = *reinterpret_cast<_Float16*>(&hi.x);
    r[3] = *reinterpret_cast<_Float16*>(&hi.y);
    return r;
}

// ---------------- Kernel 1: fused QKV projection (MFMA) ----------------
// grid 256 blocks x 512 threads (8 waves); block = 64 rows of x.
// XCD-pinned: batch = (bid&7)>>1, chunk = ((bid>>3)<<1)|(bid&1).
__global__ __launch_bounds__(512) void proj_kernel(
    const float* __restrict__ x,
    const float* __restrict__ Wk, const float* __restrict__ bk,
    const float* __restrict__ Wq, const float* __restrict__ bq,
    const float* __restrict__ Wv, const float* __restrict__ bv,
    half_t* __restrict__ k_ws, half_t* __restrict__ q_ws,
    unsigned char* __restrict__ vT4)
{
    __shared__ half_t xs16[64][264];  // x tile f16 (rows 16B-aligned)
    __shared__ half_t Wt[96][264];    // [Wk|Wq|Wv]^T : Wt[wcol][kdim]

    const int t = threadIdx.x;
    const int xcd = blockIdx.x & 7, slot = blockIdx.x >> 3;
    const int bb = xcd >> 1;                      // batch 0..3
    const int c64 = (slot << 1) | (xcd & 1);      // chunk 0..63
    const int row0 = bb * NN + c64 * 64;

    // stage x tile [64][256] fp32 -> f16
    const float4* x4 = reinterpret_cast<const float4*>(x) + (size_t)row0 * 64;
    for (int idx = t; idx < 64 * 64; idx += 512) {
        int r = idx >> 6, c4 = idx & 63;
        float4 v = x4[r * 64 + c4];
        half4_t h;
        h[0] = (half_t)v.x; h[1] = (half_t)v.y; h[2] = (half_t)v.z; h[3] = (half_t)v.w;
        *reinterpret_cast<half4_t*>(&xs16[r][c4 * 4]) = h;
    }

    // stage W^T (q columns pre-scaled by log2e)
    for (int idx = t; idx < 3072; idx += 512) {
        int cp = idx & 127;           // c-pair
        int rest = idx >> 7;          // 0..23
        int d4 = (rest & 7) * 4;
        int mat = rest >> 3;          // 0:k 1:q 2:v
        const float* Wm = (mat == 0) ? Wk : ((mat == 1) ? Wq : Wv);
        const float sc = (mat == 1) ? LOG2E : 1.0f;
        float4 w0 = *reinterpret_cast<const float4*>(Wm + (2 * cp) * DD + d4);
        float4 w1 = *reinterpret_cast<const float4*>(Wm + (2 * cp + 1) * DD + d4);
        int rbase = mat * 32 + d4;
        half2_t h;
        h[0] = (half_t)(w0.x * sc); h[1] = (half_t)(w1.x * sc);
        *reinterpret_cast<half2_t*>(&Wt[rbase + 0][2 * cp]) = h;
        h[0] = (half_t)(w0.y * sc); h[1] = (half_t)(w1.y * sc);
        *reinterpret_cast<half2_t*>(&Wt[rbase + 1][2 * cp]) = h;
        h[0] = (half_t)(w0.z * sc); h[1] = (half_t)(w1.z * sc);
        *reinterpret_cast<half2_t*>(&Wt[rbase + 2][2 * cp]) = h;
        h[0] = (half_t)(w0.w * sc); h[1] = (half_t)(w1.w * sc);
        *reinterpret_cast<half2_t*>(&Wt[rbase + 3][2 * cp]) = h;
    }
    __syncthreads();

    const int w = t >> 6, lane = t & 63;
    const int c = lane & 15, g = lane >> 4;
    const int rt = w >> 1;            // row tile 0..3
    const int ct0 = (w & 1) * 3;      // col tiles ct0..ct0+2

    f32x4 acc[3];
#pragma unroll
    for (int j = 0; j < 3; ++j) acc[j] = (f32x4){0.f, 0.f, 0.f, 0.f};

#pragma unroll
    for (int kk = 0; kk < 8; ++kk) {
        const int k0 = kk * 32 + g * 8;
        half8_t bfrag = *reinterpret_cast<const half8_t*>(&xs16[rt * 16 + c][k0]);
#pragma unroll
        for (int j = 0; j < 3; ++j) {
            half8_t afrag = *reinterpret_cast<const half8_t*>(&Wt[(ct0 + j) * 16 + c][k0]);
            acc[j] = MFMA_QK(afrag, bfrag, acc[j]);
        }
    }

    // store: lane holds C[xrow = rt*16+c][wcol = ct*16+4g+i]
    const int grow = row0 + rt * 16 + c;
#pragma unroll
    for (int j = 0; j < 3; ++j) {
        const int ct = ct0 + j;
        const int mat = ct >> 1;           // 0:k 1:q 2:v
        const float* bm = (mat == 0) ? bk : ((mat == 1) ? bq : bv);
        float4 bb4 = *reinterpret_cast<const float4*>(bm + (ct & 1) * 16 + g * 4);
        const int d0 = (ct & 1) * 16 + g * 4;
        if (mat < 2) {
            const float bsc = (mat == 1) ? LOG2E : 1.0f;
            half_t* dst = (mat == 0) ? k_ws : q_ws;
            half4_t h;
            h[0] = (half_t)(acc[j][0] + bb4.x * bsc);
            h[1] = (half_t)(acc[j][1] + bb4.y * bsc);
            h[2] = (half_t)(acc[j][2] + bb4.z * bsc);
            h[3] = (half_t)(acc[j][3] + bb4.w * bsc);
            *reinterpret_cast<half4_t*>(dst + (size_t)grow * DD + d0) = h;
        } else {
            // vT4 packed fp8: pair = n>>5, ko = n&31.
            // dest lane' = ((ko>>2)&3)*16 + (d&15); byte = (ko>>4)*8 + ((d>>4)<<2) + (ko&3)
            const int n = grow;
            const size_t pbase = (size_t)(n >> 5) * 1024;
            const int ko = n & 31;
            const int lanehi = ((ko >> 2) & 3) * 16;
            const int bytebase = ((ko >> 4) << 3) + (ko & 3);
            float vals[4] = {acc[j][0] + bb4.x, acc[j][1] + bb4.y,
                             acc[j][2] + bb4.z, acc[j][3] + bb4.w};
#pragma unroll
            for (int i = 0; i < 4; ++i) {
                int d = d0 + i;
                __hip_fp8_e4m3 f(vals[i]);
                vT4[pbase + (size_t)(lanehi + (d & 15)) * 16 + bytebase + ((d >> 4) << 2)] = f.__x;
            }
        }
    }
}

// ---------------- Kernel 2: flash attention + output projection ----------------
// grid 256 blocks x 512 threads (8 waves). Block = 64 q rows (4 tiles/wave).
// XCD-pinned: batch = (bid&7)>>1, qb = ((bid>>3)<<1)|(bid&1).
// Wave w: k in [w*512, (w+1)*512), 2 k-tiles of 16 per iter, 16 iters, 1-deep prefetch.
// Per iter: 2x K b128 + 1x V b128 (fp8-packed) = 3 VMEM instructions.
__global__ __launch_bounds__(512) void attn_kernel(
    const half_t* __restrict__ k_ws, const half_t* __restrict__ q_ws,
    const unsigned char* __restrict__ vT4,
    const float* __restrict__ x, const float* __restrict__ Wo,
    const float* __restrict__ bo, const float* __restrict__ gamma,
    float* __restrict__ out)
{
    __shared__ float acc_l[8][64][33];    // 67.6 KB, 33-pad -> conflict-free combine
    __shared__ float m_l[8][4][16];       // 2 KB
    __shared__ float s_l[8][4][16];       // 2 KB
    __shared__ half_t feat_h[64 * 40];    // 5 KB  feat f16, 40-halves rows
    __shared__ half_t woT[256 * 40];      // 20 KB Wo^T f16: woT[c*40+d]

    const int tid = threadIdx.x;
    const int w = tid >> 6, lane = tid & 63;
    const int q = lane & 15, g = lane >> 4;
    const int xcd = blockIdx.x & 7, slot = blockIdx.x >> 3;
    const int b = xcd >> 1;                       // batch 0..3 pinned to XCD pair
    const int qb = (slot << 1) | (xcd & 1);       // 0..63
    const int q0 = qb * 64;

    // stage Wo^T as f16 (coalesced reads; 8192 elements)
#pragma unroll
    for (int it = 0; it < 16; ++it) {
        int idx = tid + it * 512;
        int c = idx & 255, d = idx >> 8;
        woT[c * 40 + d] = (half_t)Wo[d * CC + c];
    }

    // Q fragments (B-operand of S^T = K*Q^T), pre-scaled by log2e
    half8_t qf[4];
#pragma unroll
    for (int t = 0; t < 4; ++t)
        qf[t] = *reinterpret_cast<const half8_t*>(
            q_ws + (size_t)(b * NN + q0 + t * 16 + q) * DD + g * 8);

    float m[4], ssum[4];
    f32x4 accd0[4], accd1[4];
#pragma unroll
    for (int t = 0; t < 4; ++t) {
        m[t] = -3.0e38f; ssum[t] = 0.f;
        accd0[t] = (f32x4){0.f, 0.f, 0.f, 0.f};
        accd1[t] = (f32x4){0.f, 0.f, 0.f, 0.f};
    }

    const half_t* kbase = k_ws + ((size_t)b * NN + q) * DD + g * 8;
    // vT4: per batch 128 pairs x 1024 B; lane reads its own 16 B slot
    const unsigned char* vb4 = vT4 + (size_t)b * 131072 + (size_t)lane * 16
                             + (size_t)w * 16 * 1024;

    const int ktbase = w * 32;

    // prologue: iteration 0's K and V
    half8_t kc0 = *reinterpret_cast<const half8_t*>(kbase + (size_t)(ktbase + 0) * 16 * DD);
    half8_t kc1 = *reinterpret_cast<const half8_t*>(kbase + (size_t)(ktbase + 1) * 16 * DD);
    uint4 vvc = *reinterpret_cast<const uint4*>(vb4);

    for (int it = 0; it < 16; ++it) {
        const int kt = ktbase + it * 2;
        const int itn = (it < 15) ? (it + 1) : it;
        const int ktn = ktbase + itn * 2;

        // prefetch next iteration's K and V
        half8_t kn0 = *reinterpret_cast<const half8_t*>(kbase + (size_t)(ktn + 0) * 16 * DD);
        half8_t kn1 = *reinterpret_cast<const half8_t*>(kbase + (size_t)(ktn + 1) * 16 * DD);
        uint4 vvn = *reinterpret_cast<const uint4*>(vb4 + (size_t)itn * 1024);

        // QK^T: 8 MFMAs (4 q-tiles x 2 k-tiles) on resident K
        f32x4 z = {0.f, 0.f, 0.f, 0.f};
        f32x4 s0[4], s1[4];
#pragma unroll
        for (int t = 0; t < 4; ++t) {
            s0[t] = MFMA_QK(kc0, qf[t], z);
            s1[t] = MFMA_QK(kc1, qf[t], z);
        }

        float tmax[4];
        bool need = false;
#pragma unroll
        for (int t = 0; t < 4; ++t) {
            float t0 = fmaxf(fmaxf(s0[t][0], s0[t][1]), fmaxf(s0[t][2], s0[t][3]));
            float t1 = fmaxf(fmaxf(s1[t][0], s1[t][1]), fmaxf(s1[t][2], s1[t][3]));
            tmax[t] = fmaxf(t0, t1);
            need = need || (tmax[t] > m[t] + THR2);
        }

        // defer-max: rescale only when some lane/tile exceeds headroom
        if (__any(need)) {
#pragma unroll
            for (int t = 0; t < 4; ++t) {
                float rmax = tmax[t];
                rmax = fmaxf(rmax, __shfl_xor(rmax, 16));
                rmax = fmaxf(rmax, __shfl_xor(rmax, 32));
                float mn = fmaxf(m[t], rmax);
                float sc = fexp2(m[t] - mn);
                ssum[t] *= sc;
                accd0[t] *= sc;
                accd1[t] *= sc;
                m[t] = mn;
            }
        }

        // decode V fp8 -> f16 (both k-tiles, both d-halves)
        half4_t va0 = fp8x4_to_half4(vvc.x);
        half4_t va1 = fp8x4_to_half4(vvc.y);
        half4_t vc0 = fp8x4_to_half4(vvc.z);
        half4_t vc1 = fp8x4_to_half4(vvc.w);

        // softmax (log2 domain) + PV per q-tile
#pragma unroll
        for (int t = 0; t < 4; ++t) {
            float p00 = fexp2(s0[t][0] - m[t]), p01 = fexp2(s0[t][1] - m[t]);
            float p02 = fexp2(s0[t][2] - m[t]), p03 = fexp2(s0[t][3] - m[t]);
            float p10 = fexp2(s1[t][0] - m[t]), p11 = fexp2(s1[t][1] - m[t]);
            float p12 = fexp2(s1[t][2] - m[t]), p13 = fexp2(s1[t][3] - m[t]);
            ssum[t] += ((p00 + p01) + (p02 + p03)) + ((p10 + p11) + (p12 + p13));

            half4_t pf0, pf1;
            pf0[0] = (half_t)p00; pf0[1] = (half_t)p01; pf0[2] = (half_t)p02; pf0[3] = (half_t)p03;
            pf1[0] = (half_t)p10; pf1[1] = (half_t)p11; pf1[2] = (half_t)p12; pf1[3] = (half_t)p13;

            accd0[t] = MFMA_PV(va0, pf0, accd0[t]);
            accd1[t] = MFMA_PV(va1, pf0, accd1[t]);
            accd0[t] = MFMA_PV(vc0, pf1, accd0[t]);
            accd1[t] = MFMA_PV(vc1, pf1, accd1[t]);
        }

        kc0 = kn0; kc1 = kn1; vvc = vvn;
    }

    // fold lane-local ssum to row sums
#pragma unroll
    for (int t = 0; t < 4; ++t) {
        ssum[t] += __shfl_xor(ssum[t], 16);
        ssum[t] += __shfl_xor(ssum[t], 32);
    }

    if (lane < 16) {
#pragma unroll
        for (int t = 0; t < 4; ++t) { m_l[w][t][lane] = m[t]; s_l[w][t][lane] = ssum[t]; }
    }
#pragma unroll
    for (int t = 0; t < 4; ++t)
#pragma unroll
        for (int i = 0; i < 4; ++i) {
            acc_l[w][lane][t * 8 + i] = accd0[t][i];
            acc_l[w][lane][t * 8 + 4 + i] = accd1[t][i];
        }
    __syncthreads();

    // waves 0..3 combine the 8 k-splits; wave w handles q-tile t=w.
    if (w < 4) {
        const int t = w;
        float M = m_l[0][t][q];
#pragma unroll
        for (int ww = 1; ww < 8; ++ww) M = fmaxf(M, m_l[ww][t][q]);
        float SS = 0.f;
        float f[8] = {0.f, 0.f, 0.f, 0.f, 0.f, 0.f, 0.f, 0.f};
#pragma unroll
        for (int ww = 0; ww < 8; ++ww) {
            float sc = fexp2(m_l[ww][t][q] - M);
            SS += s_l[ww][t][q] * sc;
#pragma unroll
            for (int i = 0; i < 8; ++i) f[i] += acc_l[ww][lane][t * 8 + i] * sc;
        }
        float inv = 1.0f / SS;
        half4_t h0, h1;
#pragma unroll
        for (int i = 0; i < 4; ++i) { h0[i] = (half_t)(f[i] * inv); h1[i] = (half_t)(f[4 + i] * inv); }
        *reinterpret_cast<half4_t*>(&feat_h[(t * 16 + q) * 40 + g * 4]) = h0;
        *reinterpret_cast<half4_t*>(&feat_h[(t * 16 + q) * 40 + 16 + g * 4]) = h1;
    }
    __syncthreads();

    // ---- MFMA epilogue: O[r][c] = gamma*(feat@Wo + bo) + x ----
    const float gam = gamma[0];
#pragma unroll
    for (int j = 0; j < 2; ++j) {
        const int ct = w * 2 + j;
        half8_t kfe = *reinterpret_cast<const half8_t*>(&woT[(ct * 16 + q) * 40 + g * 8]);
        float4 bb4 = *reinterpret_cast<const float4*>(bo + ct * 16 + g * 4);
#pragma unroll
        for (int rt = 0; rt < 4; ++rt) {
            half8_t qfe = *reinterpret_cast<const half8_t*>(&feat_h[(rt * 16 + q) * 40 + g * 8]);
            f32x4 z = {0.f, 0.f, 0.f, 0.f};
            f32x4 o = MFMA_QK(kfe, qfe, z);
            const size_t base = ((size_t)b * NN + q0 + rt * 16 + q) * CC + ct * 16 + g * 4;
            float4 xv = *reinterpret_cast<const float4*>(x + base);
            float4 ov;
            ov.x = gam * (o[0] + bb4.x) + xv.x;
            ov.y = gam * (o[1] + bb4.y) + xv.y;
            ov.z = gam * (o[2] + bb4.z) + xv.z;
            ov.w = gam * (o[3] + bb4.w) + xv.w;
            *reinterpret_cast<float4*>(out + base) = ov;
        }
    }
}

// ---------------- launch ----------------
extern "C" void kernel_launch(void* const* d_in, const int* in_sizes, int n_in,
                              void* d_out, int out_size, void* d_ws, size_t ws_size,
                              hipStream_t stream) {
    const float* x  = (const float*)d_in[0];
    const float* Wk = (const float*)d_in[1];
    const float* bk = (const float*)d_in[2];
    const float* Wq = (const float*)d_in[3];
    const float* bq = (const float*)d_in[4];
    const float* Wv = (const float*)d_in[5];
    const float* bv = (const float*)d_in[6];
    const float* Wo = (const float*)d_in[7];
    const float* bo = (const float*)d_in[8];
    const float* gamma = (const float*)d_in[9];
    float* out = (float*)d_out;

    half_t* k_ws = (half_t*)d_ws;
    half_t* q_ws = k_ws + (size_t)BB * NN * DD;
    unsigned char* vT4 = (unsigned char*)(q_ws + (size_t)BB * NN * DD);

    proj_kernel<<<256, 512, 0, stream>>>(x, Wk, bk, Wq, bq, Wv, bv, k_ws, q_ws, vT4);
    attn_kernel<<<256, 512, 0, stream>>>(k_ws, q_ws, vT4, x, Wo, bo, gamma, out);
}

// Round 16
// 45.674 us; speedup vs baseline: 1.4293x; 1.4293x over previous
//
#include <hip/hip_runtime.h>
#include <hip/hip_bf16.h>
#include <hip/hip_fp16.h>

// Self-attention: B=4, N=4096 (64x64 spatial), C=256, D=32.
//   proj_kernel  : MFMA GEMM (~2.5us, validated). k,q row-major [B*N][32] f16
//                  (q pre-scaled by log2e); v packed per-consumer-lane f16:
//                  vT3[gtile][lane][16B], lane=(g<<4)|q holds {V[q][4k],V[16+q][4k]}.
//   attn_partial : grid 256 = 16 qu(256 rows) x 4 b x 4 ks. 8 waves, wave = TWO
//                  q-tiles x 1024 k. K/V streamed through LDS in 8 chunks of
//                  128 k (16 KB), double-buffered, reg-staged (loads issued a
//                  full compute-phase before their ds_write -> latency hidden,
//                  ONE barrier per chunk); every staged line serves all 8 waves
//                  and 256 q-rows -> 4x fewer line fills per CU than R10.
//   attn_combine : exact softmax merge of 4 k-split partials + MFMA Wo-epilogue
//                  (Wo^T in LDS) + gamma*(..)+x residual. (R11-verified)

#define BB 4
#define NN 4096
#define CC 256
#define DD 32
#define LOG2E 1.44269504088896340736f
#define THR2 11.0f
#define NROW (BB * NN)      // 16384
#define KSPLIT 4
#define NCH 8               // chunks of 128 k per block (8 k-tiles each)

typedef _Float16 half_t;
typedef _Float16 half2_t __attribute__((ext_vector_type(2)));
typedef _Float16 half4_t __attribute__((ext_vector_type(4)));
typedef _Float16 half8_t __attribute__((ext_vector_type(8)));
typedef float f32x4 __attribute__((ext_vector_type(4)));

#define MFMA_QK(a, b, c) __builtin_amdgcn_mfma_f32_16x16x32_f16(a, b, c, 0, 0, 0)
#define MFMA_PV(a, b, c) __builtin_amdgcn_mfma_f32_16x16x16f16(a, b, c, 0, 0, 0)

static __device__ inline float fexp2(float x) {
#if __has_builtin(__builtin_amdgcn_exp2f)
    return __builtin_amdgcn_exp2f(x);
#else
    return exp2f(x);
#endif
}

// ---------------- Kernel 1: fused QKV projection (MFMA) ----------------
// grid 256 blocks x 512 threads (8 waves); block = 64 rows of x. XCD-pinned.
__global__ __launch_bounds__(512) void proj_kernel(
    const float* __restrict__ x,
    const float* __restrict__ Wk, const float* __restrict__ bk,
    const float* __restrict__ Wq, const float* __restrict__ bq,
    const float* __restrict__ Wv, const float* __restrict__ bv,
    half_t* __restrict__ k_ws, half_t* __restrict__ q_ws, half_t* __restrict__ vT3)
{
    __shared__ half_t xs16[64][264];  // x tile f16 (rows 16B-aligned)
    __shared__ half_t Wt[96][264];    // [Wk|Wq|Wv]^T : Wt[wcol][kdim]

    const int t = threadIdx.x;
    const int xcd = blockIdx.x & 7, slot = blockIdx.x >> 3;
    const int bb = xcd >> 1;                      // batch 0..3
    const int c64 = (slot << 1) | (xcd & 1);      // chunk 0..63
    const int row0 = bb * NN + c64 * 64;

    // stage x tile [64][256] fp32 -> f16
    const float4* x4 = reinterpret_cast<const float4*>(x) + (size_t)row0 * 64;
    for (int idx = t; idx < 64 * 64; idx += 512) {
        int r = idx >> 6, c4 = idx & 63;
        float4 v = x4[r * 64 + c4];
        half4_t h;
        h[0] = (half_t)v.x; h[1] = (half_t)v.y; h[2] = (half_t)v.z; h[3] = (half_t)v.w;
        *reinterpret_cast<half4_t*>(&xs16[r][c4 * 4]) = h;
    }

    // stage W^T (q columns pre-scaled by log2e)
    for (int idx = t; idx < 3072; idx += 512) {
        int cp = idx & 127;           // c-pair
        int rest = idx >> 7;          // 0..23
        int d4 = (rest & 7) * 4;
        int mat = rest >> 3;          // 0:k 1:q 2:v
        const float* Wm = (mat == 0) ? Wk : ((mat == 1) ? Wq : Wv);
        const float sc = (mat == 1) ? LOG2E : 1.0f;
        float4 w0 = *reinterpret_cast<const float4*>(Wm + (2 * cp) * DD + d4);
        float4 w1 = *reinterpret_cast<const float4*>(Wm + (2 * cp + 1) * DD + d4);
        int rbase = mat * 32 + d4;
        half2_t h;
        h[0] = (half_t)(w0.x * sc); h[1] = (half_t)(w1.x * sc);
        *reinterpret_cast<half2_t*>(&Wt[rbase + 0][2 * cp]) = h;
        h[0] = (half_t)(w0.y * sc); h[1] = (half_t)(w1.y * sc);
        *reinterpret_cast<half2_t*>(&Wt[rbase + 1][2 * cp]) = h;
        h[0] = (half_t)(w0.z * sc); h[1] = (half_t)(w1.z * sc);
        *reinterpret_cast<half2_t*>(&Wt[rbase + 2][2 * cp]) = h;
        h[0] = (half_t)(w0.w * sc); h[1] = (half_t)(w1.w * sc);
        *reinterpret_cast<half2_t*>(&Wt[rbase + 3][2 * cp]) = h;
    }
    __syncthreads();

    const int w = t >> 6, lane = t & 63;
    const int c = lane & 15, g = lane >> 4;
    const int rt = w >> 1;            // row tile 0..3
    const int ct0 = (w & 1) * 3;      // col tiles ct0..ct0+2

    f32x4 acc[3];
#pragma unroll
    for (int j = 0; j < 3; ++j) acc[j] = (f32x4){0.f, 0.f, 0.f, 0.f};

#pragma unroll
    for (int kk = 0; kk < 8; ++kk) {
        const int k0 = kk * 32 + g * 8;
        half8_t bfrag = *reinterpret_cast<const half8_t*>(&xs16[rt * 16 + c][k0]);
#pragma unroll
        for (int j = 0; j < 3; ++j) {
            half8_t afrag = *reinterpret_cast<const half8_t*>(&Wt[(ct0 + j) * 16 + c][k0]);
            acc[j] = MFMA_QK(afrag, bfrag, acc[j]);
        }
    }

    // store: lane holds C[xrow = rt*16+c][wcol = ct*16+4g+i]
    const int grow = row0 + rt * 16 + c;
#pragma unroll
    for (int j = 0; j < 3; ++j) {
        const int ct = ct0 + j;
        const int mat = ct >> 1;           // 0:k 1:q 2:v
        const float* bm = (mat == 0) ? bk : ((mat == 1) ? bq : bv);
        float4 bb4 = *reinterpret_cast<const float4*>(bm + (ct & 1) * 16 + g * 4);
        const int d0 = (ct & 1) * 16 + g * 4;
        if (mat < 2) {
            const float bsc = (mat == 1) ? LOG2E : 1.0f;
            half_t* dst = (mat == 0) ? k_ws : q_ws;
            half4_t h;
            h[0] = (half_t)(acc[j][0] + bb4.x * bsc);
            h[1] = (half_t)(acc[j][1] + bb4.y * bsc);
            h[2] = (half_t)(acc[j][2] + bb4.z * bsc);
            h[3] = (half_t)(acc[j][3] + bb4.w * bsc);
            *reinterpret_cast<half4_t*>(dst + (size_t)grow * DD + d0) = h;
        } else {
            // vT3 packed f16: gtile = grow>>4, kk' = grow&15 == c.
            // half index: l = (kk'>>2)*16 + (d&15); h = l*8 + (d>=16?4:0) + (kk'&3)
            const size_t tbase = (size_t)(grow >> 4) * 512;
            float vals[4] = {acc[j][0] + bb4.x, acc[j][1] + bb4.y,
                             acc[j][2] + bb4.z, acc[j][3] + bb4.w};
#pragma unroll
            for (int i = 0; i < 4; ++i) {
                int d = d0 + i;
                int l = ((c >> 2) << 4) | (d & 15);
                int h = l * 8 + ((d >> 4) << 2) + (c & 3);
                vT3[tbase + h] = (half_t)vals[i];
            }
        }
    }
}

// ---------------- Kernel 2: q-split/k-split flash attention partial ----------------
// grid 256 x 512 threads (8 waves). Block = 256 q-rows x 1024 k (k-quarter ks).
// Wave w owns q-tiles {2w, 2w+1} across the block's 1024 k.
// K/V streamed via LDS in 8 double-buffered chunks of 8 k-tiles (128 k).
__global__ __launch_bounds__(512) void attn_partial(
    const half_t* __restrict__ k_ws, const half_t* __restrict__ q_ws,
    const half_t* __restrict__ vT3,
    float* __restrict__ pm, float* __restrict__ ps, float* __restrict__ pO)
{
    __shared__ half_t kbuf[2][8][512];   // 16 KB: [buf][ktile][lane-major 16B frags]
    __shared__ half_t vbuf[2][8][512];   // 16 KB

    const int tid = threadIdx.x;
    const int w = tid >> 6, lane = tid & 63;
    const int q = lane & 15, g = lane >> 4;
    // XCD pinning: batch -> XCD pair
    const int xcd = blockIdx.x & 7, rest = blockIdx.x >> 3;
    const int b = xcd >> 1;
    const int u = (rest << 1) | (xcd & 1);   // 0..63
    const int qu = u >> 2;                   // 0..15 (256-row unit)
    const int ks = u & 3;                    // k quarter
    const int r0 = b * NN + qu * 256;

    // Q fragments for this wave's two q-tiles (pre-scaled by log2e)
    half8_t qf0 = *reinterpret_cast<const half8_t*>(
        q_ws + (size_t)(r0 + (2 * w + 0) * 16 + q) * DD + g * 8);
    half8_t qf1 = *reinterpret_cast<const half8_t*>(
        q_ws + (size_t)(r0 + (2 * w + 1) * 16 + q) * DD + g * 8);

    float m0 = -3.0e38f, m1 = -3.0e38f, ss0 = 0.f, ss1 = 0.f;
    f32x4 acc00 = {0.f, 0.f, 0.f, 0.f};   // q-tile 0, d = 4g+i
    f32x4 acc01 = {0.f, 0.f, 0.f, 0.f};   // q-tile 0, d = 16+4g+i
    f32x4 acc10 = {0.f, 0.f, 0.f, 0.f};   // q-tile 1
    f32x4 acc11 = {0.f, 0.f, 0.f, 0.f};

    const int t0 = ks * 64;              // k-tile base within batch (64 tiles = 1024 k)
    // staging sources for wave w (one K tile + one V tile per chunk)
    const half_t* ksrc = k_ws + ((size_t)b * NN + q) * DD + g * 8;  // + tile*16*DD
    const half_t* vsrc = vT3 + (size_t)lane * 8;                    // + gtile*512

    // prologue: stage chunk 0 (wave w stages local tile w)
    {
        half8_t sK = *reinterpret_cast<const half8_t*>(ksrc + (size_t)(t0 + w) * 16 * DD);
        half8_t sV = *reinterpret_cast<const half8_t*>(vsrc + (size_t)(b * 256 + t0 + w) * 512);
        *reinterpret_cast<half8_t*>(&kbuf[0][w][lane * 8]) = sK;
        *reinterpret_cast<half8_t*>(&vbuf[0][w][lane * 8]) = sV;
    }
    __syncthreads();

    for (int ch = 0; ch < NCH; ++ch) {
        const int cb = ch & 1;

        // issue next chunk's loads now (ds_write happens after this chunk's compute)
        half8_t sK, sV;
        if (ch + 1 < NCH) {
            const int lt = t0 + (ch + 1) * 8 + w;
            sK = *reinterpret_cast<const half8_t*>(ksrc + (size_t)lt * 16 * DD);
            sV = *reinterpret_cast<const half8_t*>(vsrc + (size_t)(b * 256 + lt) * 512);
        }

        // compute 8 k-tiles from buf[cb], 2 q-tiles each
#pragma unroll
        for (int t = 0; t < 8; ++t) {
            half8_t kf = *reinterpret_cast<const half8_t*>(&kbuf[cb][t][lane * 8]);
            half8_t vv = *reinterpret_cast<const half8_t*>(&vbuf[cb][t][lane * 8]);

            f32x4 z = {0.f, 0.f, 0.f, 0.f};
            f32x4 sA = MFMA_QK(kf, qf0, z);
            f32x4 sB = MFMA_QK(kf, qf1, z);

            float tA = fmaxf(fmaxf(sA[0], sA[1]), fmaxf(sA[2], sA[3]));
            float tB = fmaxf(fmaxf(sB[0], sB[1]), fmaxf(sB[2], sB[3]));
            bool need = (tA > m0 + THR2) || (tB > m1 + THR2);
            if (__any(need)) {
                float rA = fmaxf(tA, __shfl_xor(tA, 16));
                rA = fmaxf(rA, __shfl_xor(rA, 32));
                float rB = fmaxf(tB, __shfl_xor(tB, 16));
                rB = fmaxf(rB, __shfl_xor(rB, 32));
                float n0 = fmaxf(m0, rA), n1 = fmaxf(m1, rB);
                float c0 = fexp2(m0 - n0), c1 = fexp2(m1 - n1);
                ss0 *= c0; ss1 *= c1;
                acc00 *= c0; acc01 *= c0;
                acc10 *= c1; acc11 *= c1;
                m0 = n0; m1 = n1;
            }

            float pA0 = fexp2(sA[0] - m0), pA1 = fexp2(sA[1] - m0);
            float pA2 = fexp2(sA[2] - m0), pA3 = fexp2(sA[3] - m0);
            float pB0 = fexp2(sB[0] - m1), pB1 = fexp2(sB[1] - m1);
            float pB2 = fexp2(sB[2] - m1), pB3 = fexp2(sB[3] - m1);
            ss0 += (pA0 + pA1) + (pA2 + pA3);
            ss1 += (pB0 + pB1) + (pB2 + pB3);

            half4_t pf0, pf1;
            pf0[0] = (half_t)pA0; pf0[1] = (half_t)pA1; pf0[2] = (half_t)pA2; pf0[3] = (half_t)pA3;
            pf1[0] = (half_t)pB0; pf1[1] = (half_t)pB1; pf1[2] = (half_t)pB2; pf1[3] = (half_t)pB3;

            half4_t va0 = __builtin_shufflevector(vv, vv, 0, 1, 2, 3);
            half4_t va1 = __builtin_shufflevector(vv, vv, 4, 5, 6, 7);

            acc00 = MFMA_PV(va0, pf0, acc00);
            acc01 = MFMA_PV(va1, pf0, acc01);
            acc10 = MFMA_PV(va0, pf1, acc10);
            acc11 = MFMA_PV(va1, pf1, acc11);
        }

        // write next chunk into the other buffer, then one barrier
        if (ch + 1 < NCH) {
            *reinterpret_cast<half8_t*>(&kbuf[cb ^ 1][w][lane * 8]) = sK;
            *reinterpret_cast<half8_t*>(&vbuf[cb ^ 1][w][lane * 8]) = sV;
        }
        __syncthreads();
    }

    // fold lane-local ssum to row sums
    ss0 += __shfl_xor(ss0, 16);
    ss0 += __shfl_xor(ss0, 32);
    ss1 += __shfl_xor(ss1, 16);
    ss1 += __shfl_xor(ss1, 32);

    // write partials: pm/ps per row; pO[(ks*NROW + r)*32 + d]
    if (lane < 16) {
        pm[(size_t)ks * NROW + r0 + (2 * w + 0) * 16 + lane] = m0;
        ps[(size_t)ks * NROW + r0 + (2 * w + 0) * 16 + lane] = ss0;
        pm[(size_t)ks * NROW + r0 + (2 * w + 1) * 16 + lane] = m1;
        ps[(size_t)ks * NROW + r0 + (2 * w + 1) * 16 + lane] = ss1;
    }
    {
        const int rA = r0 + (2 * w + 0) * 16 + q;
        float* po = pO + ((size_t)ks * NROW + rA) * 32;
        *reinterpret_cast<f32x4*>(po + g * 4) = acc00;
        *reinterpret_cast<f32x4*>(po + 16 + g * 4) = acc01;
    }
    {
        const int rB = r0 + (2 * w + 1) * 16 + q;
        float* po = pO + ((size_t)ks * NROW + rB) * 32;
        *reinterpret_cast<f32x4*>(po + g * 4) = acc10;
        *reinterpret_cast<f32x4*>(po + 16 + g * 4) = acc11;
    }
}

// ---------------- Kernel 3: combine + output projection ----------------
// grid 256 blocks (b*64+qb) x 512 threads. Block = 64 q-rows. (R11-verified)
__global__ __launch_bounds__(512) void attn_combine(
    const float* __restrict__ pm, const float* __restrict__ ps,
    const float* __restrict__ pO,
    const float* __restrict__ x, const float* __restrict__ Wo,
    const float* __restrict__ bo, const float* __restrict__ gamma,
    float* __restrict__ out)
{
    __shared__ half_t feat_h[64 * 40];    // 5 KB
    __shared__ half_t woT[256 * 40];      // 20 KB Wo^T f16: woT[c*40+d]

    const int tid = threadIdx.x;
    const int b = blockIdx.x >> 6, qb = blockIdx.x & 63;
    const int q0 = qb * 64;
    const int r0 = b * NN + q0;

    // stage Wo^T as f16
#pragma unroll
    for (int it = 0; it < 16; ++it) {
        int idx = tid + it * 512;
        int c = idx & 255, d = idx >> 8;
        woT[c * 40 + d] = (half_t)Wo[d * CC + c];
    }

    // exact softmax merge of 4 k-split partials: thread -> (r = tid>>3, d4 = (tid&7)*4)
    {
        const int r = tid >> 3, d4 = (tid & 7) * 4;
        const int gr = r0 + r;
        float mv[4];
        float M = -3.0e38f;
#pragma unroll
        for (int k = 0; k < KSPLIT; ++k) {
            mv[k] = pm[(size_t)k * NROW + gr];
            M = fmaxf(M, mv[k]);
        }
        float S = 0.f;
        f32x4 f = {0.f, 0.f, 0.f, 0.f};
#pragma unroll
        for (int k = 0; k < KSPLIT; ++k) {
            float wgt = fexp2(mv[k] - M);
            S += ps[(size_t)k * NROW + gr] * wgt;
            f32x4 p = *reinterpret_cast<const f32x4*>(pO + ((size_t)k * NROW + gr) * 32 + d4);
            f += p * wgt;
        }
        float inv = 1.0f / S;
#pragma unroll
        for (int i = 0; i < 4; ++i) feat_h[r * 40 + d4 + i] = (half_t)(f[i] * inv);
    }
    __syncthreads();

    // MFMA epilogue: O[r][c] = gamma*(feat@Wo + bo) + x  (validated structure)
    const int w = tid >> 6, lane = tid & 63;
    const int q = lane & 15, g = lane >> 4;
    const float gam = gamma[0];
#pragma unroll
    for (int j = 0; j < 2; ++j) {
        const int ct = w * 2 + j;
        half8_t kfe = *reinterpret_cast<const half8_t*>(&woT[(ct * 16 + q) * 40 + g * 8]);
        float4 bb4 = *reinterpret_cast<const float4*>(bo + ct * 16 + g * 4);
#pragma unroll
        for (int rt = 0; rt < 4; ++rt) {
            half8_t qfe = *reinterpret_cast<const half8_t*>(&feat_h[(rt * 16 + q) * 40 + g * 8]);
            f32x4 z = {0.f, 0.f, 0.f, 0.f};
            f32x4 o = MFMA_QK(kfe, qfe, z);
            const size_t base = ((size_t)b * NN + q0 + rt * 16 + q) * CC + ct * 16 + g * 4;
            float4 xv = *reinterpret_cast<const float4*>(x + base);
            float4 ov;
            ov.x = gam * (o[0] + bb4.x) + xv.x;
            ov.y = gam * (o[1] + bb4.y) + xv.y;
            ov.z = gam * (o[2] + bb4.z) + xv.z;
            ov.w = gam * (o[3] + bb4.w) + xv.w;
            *reinterpret_cast<float4*>(out + base) = ov;
        }
    }
}

// ---------------- launch ----------------
extern "C" void kernel_launch(void* const* d_in, const int* in_sizes, int n_in,
                              void* d_out, int out_size, void* d_ws, size_t ws_size,
                              hipStream_t stream) {
    const float* x  = (const float*)d_in[0];
    const float* Wk = (const float*)d_in[1];
    const float* bk = (const float*)d_in[2];
    const float* Wq = (const float*)d_in[3];
    const float* bq = (const float*)d_in[4];
    const float* Wv = (const float*)d_in[5];
    const float* bv = (const float*)d_in[6];
    const float* Wo = (const float*)d_in[7];
    const float* bo = (const float*)d_in[8];
    const float* gamma = (const float*)d_in[9];
    float* out = (float*)d_out;

    half_t* k_ws = (half_t*)d_ws;
    half_t* q_ws = k_ws + (size_t)BB * NN * DD;
    half_t* vT3  = q_ws + (size_t)BB * NN * DD;
    float*  pm   = (float*)(vT3 + (size_t)BB * NN * DD);
    float*  ps   = pm + (size_t)KSPLIT * NROW;
    float*  pO   = ps + (size_t)KSPLIT * NROW;

    proj_kernel<<<256, 512, 0, stream>>>(x, Wk, bk, Wq, bq, Wv, bv, k_ws, q_ws, vT3);
    attn_partial<<<256, 512, 0, stream>>>(k_ws, q_ws, vT3, pm, ps, pO);
    attn_combine<<<256, 512, 0, stream>>>(pm, ps, pO, x, Wo, bo, gamma, out);
}

// Round 18
// 44.308 us; speedup vs baseline: 1.4734x; 1.0308x over previous
//
#include <hip/hip_runtime.h>
#include <hip/hip_bf16.h>
#include <hip/hip_fp16.h>

// Self-attention: B=4, N=4096 (64x64 spatial), C=256, D=32.
//   proj_kernel  : MFMA GEMM (~2.5us, validated). k,q row-major [B*N][32] f16
//                  (q pre-scaled by log2e); v packed per-consumer-lane f16:
//                  vT3[gtile][lane][16B], lane=(g<<4)|q holds {V[q][4k],V[16+q][4k]}.
//   attn_partial : grid 512 = 32 qb(128 rows) x 4 b x 4 ks -> 2 blocks/CU =
//                  4 waves/SIMD (R15 ran 2 waves/SIMD -> VALU ~50% idle on the
//                  softmax dependency chain). 8 waves, wave = ONE q-tile x 1024 k.
//                  K/V streamed through LDS in 8 chunks of 128 k, double-buffered,
//                  reg-staged (R15-validated pattern).
//   attn_combine : exact softmax merge of 4 k-split partials + MFMA Wo-epilogue
//                  (Wo^T in LDS) + gamma*(..)+x residual. (R15-verified, unchanged)

#define BB 4
#define NN 4096
#define CC 256
#define DD 32
#define LOG2E 1.44269504088896340736f
#define THR2 11.0f
#define NROW (BB * NN)      // 16384
#define KSPLIT 4
#define NCH 8               // chunks of 128 k per block (8 k-tiles each)

typedef _Float16 half_t;
typedef _Float16 half2_t __attribute__((ext_vector_type(2)));
typedef _Float16 half4_t __attribute__((ext_vector_type(4)));
typedef _Float16 half8_t __attribute__((ext_vector_type(8)));
typedef float f32x4 __attribute__((ext_vector_type(4)));

#define MFMA_QK(a, b, c) __builtin_amdgcn_mfma_f32_16x16x32_f16(a, b, c, 0, 0, 0)
#define MFMA_PV(a, b, c) __builtin_amdgcn_mfma_f32_16x16x16f16(a, b, c, 0, 0, 0)

static __device__ inline float fexp2(float x) {
#if __has_builtin(__builtin_amdgcn_exp2f)
    return __builtin_amdgcn_exp2f(x);
#else
    return exp2f(x);
#endif
}

// pack two f32 -> 2x f16 (v_cvt_pkrtz_f16_f32), with explicit type bridge
static __device__ __forceinline__ half2_t pk_f16(float a, float b) {
    auto r = __builtin_amdgcn_cvt_pkrtz(a, b);   // __fp16 ext_vector(2)
    return *reinterpret_cast<half2_t*>(&r);
}

// ---------------- Kernel 1: fused QKV projection (MFMA) ----------------
// grid 256 blocks x 512 threads (8 waves); block = 64 rows of x. XCD-pinned.
__global__ __launch_bounds__(512) void proj_kernel(
    const float* __restrict__ x,
    const float* __restrict__ Wk, const float* __restrict__ bk,
    const float* __restrict__ Wq, const float* __restrict__ bq,
    const float* __restrict__ Wv, const float* __restrict__ bv,
    half_t* __restrict__ k_ws, half_t* __restrict__ q_ws, half_t* __restrict__ vT3)
{
    __shared__ half_t xs16[64][264];  // x tile f16 (rows 16B-aligned)
    __shared__ half_t Wt[96][264];    // [Wk|Wq|Wv]^T : Wt[wcol][kdim]

    const int t = threadIdx.x;
    const int xcd = blockIdx.x & 7, slot = blockIdx.x >> 3;
    const int bb = xcd >> 1;                      // batch 0..3
    const int c64 = (slot << 1) | (xcd & 1);      // chunk 0..63
    const int row0 = bb * NN + c64 * 64;

    // stage x tile [64][256] fp32 -> f16
    const float4* x4 = reinterpret_cast<const float4*>(x) + (size_t)row0 * 64;
    for (int idx = t; idx < 64 * 64; idx += 512) {
        int r = idx >> 6, c4 = idx & 63;
        float4 v = x4[r * 64 + c4];
        half4_t h;
        h[0] = (half_t)v.x; h[1] = (half_t)v.y; h[2] = (half_t)v.z; h[3] = (half_t)v.w;
        *reinterpret_cast<half4_t*>(&xs16[r][c4 * 4]) = h;
    }

    // stage W^T (q columns pre-scaled by log2e)
    for (int idx = t; idx < 3072; idx += 512) {
        int cp = idx & 127;           // c-pair
        int rest = idx >> 7;          // 0..23
        int d4 = (rest & 7) * 4;
        int mat = rest >> 3;          // 0:k 1:q 2:v
        const float* Wm = (mat == 0) ? Wk : ((mat == 1) ? Wq : Wv);
        const float sc = (mat == 1) ? LOG2E : 1.0f;
        float4 w0 = *reinterpret_cast<const float4*>(Wm + (2 * cp) * DD + d4);
        float4 w1 = *reinterpret_cast<const float4*>(Wm + (2 * cp + 1) * DD + d4);
        int rbase = mat * 32 + d4;
        half2_t h;
        h[0] = (half_t)(w0.x * sc); h[1] = (half_t)(w1.x * sc);
        *reinterpret_cast<half2_t*>(&Wt[rbase + 0][2 * cp]) = h;
        h[0] = (half_t)(w0.y * sc); h[1] = (half_t)(w1.y * sc);
        *reinterpret_cast<half2_t*>(&Wt[rbase + 1][2 * cp]) = h;
        h[0] = (half_t)(w0.z * sc); h[1] = (half_t)(w1.z * sc);
        *reinterpret_cast<half2_t*>(&Wt[rbase + 2][2 * cp]) = h;
        h[0] = (half_t)(w0.w * sc); h[1] = (half_t)(w1.w * sc);
        *reinterpret_cast<half2_t*>(&Wt[rbase + 3][2 * cp]) = h;
    }
    __syncthreads();

    const int w = t >> 6, lane = t & 63;
    const int c = lane & 15, g = lane >> 4;
    const int rt = w >> 1;            // row tile 0..3
    const int ct0 = (w & 1) * 3;      // col tiles ct0..ct0+2

    f32x4 acc[3];
#pragma unroll
    for (int j = 0; j < 3; ++j) acc[j] = (f32x4){0.f, 0.f, 0.f, 0.f};

#pragma unroll
    for (int kk = 0; kk < 8; ++kk) {
        const int k0 = kk * 32 + g * 8;
        half8_t bfrag = *reinterpret_cast<const half8_t*>(&xs16[rt * 16 + c][k0]);
#pragma unroll
        for (int j = 0; j < 3; ++j) {
            half8_t afrag = *reinterpret_cast<const half8_t*>(&Wt[(ct0 + j) * 16 + c][k0]);
            acc[j] = MFMA_QK(afrag, bfrag, acc[j]);
        }
    }

    // store: lane holds C[xrow = rt*16+c][wcol = ct*16+4g+i]
    const int grow = row0 + rt * 16 + c;
#pragma unroll
    for (int j = 0; j < 3; ++j) {
        const int ct = ct0 + j;
        const int mat = ct >> 1;           // 0:k 1:q 2:v
        const float* bm = (mat == 0) ? bk : ((mat == 1) ? bq : bv);
        float4 bb4 = *reinterpret_cast<const float4*>(bm + (ct & 1) * 16 + g * 4);
        const int d0 = (ct & 1) * 16 + g * 4;
        if (mat < 2) {
            const float bsc = (mat == 1) ? LOG2E : 1.0f;
            half_t* dst = (mat == 0) ? k_ws : q_ws;
            half4_t h;
            h[0] = (half_t)(acc[j][0] + bb4.x * bsc);
            h[1] = (half_t)(acc[j][1] + bb4.y * bsc);
            h[2] = (half_t)(acc[j][2] + bb4.z * bsc);
            h[3] = (half_t)(acc[j][3] + bb4.w * bsc);
            *reinterpret_cast<half4_t*>(dst + (size_t)grow * DD + d0) = h;
        } else {
            // vT3 packed f16: gtile = grow>>4, kk' = grow&15 == c.
            // half index: l = (kk'>>2)*16 + (d&15); h = l*8 + (d>=16?4:0) + (kk'&3)
            const size_t tbase = (size_t)(grow >> 4) * 512;
            float vals[4] = {acc[j][0] + bb4.x, acc[j][1] + bb4.y,
                             acc[j][2] + bb4.z, acc[j][3] + bb4.w};
#pragma unroll
            for (int i = 0; i < 4; ++i) {
                int d = d0 + i;
                int l = ((c >> 2) << 4) | (d & 15);
                int h = l * 8 + ((d >> 4) << 2) + (c & 3);
                vT3[tbase + h] = (half_t)vals[i];
            }
        }
    }
}

// ---------------- Kernel 2: q-split/k-split flash attention partial ----------------
// grid 512 x 512 threads (8 waves), 2 blocks/CU -> 4 waves/SIMD.
// Block = 128 q-rows x 1024 k (k-quarter ks). Wave w owns q-tile w.
// K/V streamed via LDS in 8 double-buffered chunks of 8 k-tiles (128 k).
__global__ __launch_bounds__(512) void attn_partial(
    const half_t* __restrict__ k_ws, const half_t* __restrict__ q_ws,
    const half_t* __restrict__ vT3,
    float* __restrict__ pm, float* __restrict__ ps, float* __restrict__ pO)
{
    __shared__ half_t kbuf[2][8][512];   // 16 KB: [buf][ktile][lane-major 16B frags]
    __shared__ half_t vbuf[2][8][512];   // 16 KB

    const int tid = threadIdx.x;
    const int w = tid >> 6, lane = tid & 63;
    const int q = lane & 15, g = lane >> 4;
    // XCD pinning: batch -> XCD pair
    const int xcd = blockIdx.x & 7, rest = blockIdx.x >> 3;
    const int b = xcd >> 1;
    const int u = (rest << 1) | (xcd & 1);   // 0..127
    const int qb = u >> 2;                   // 0..31 (128-row block)
    const int ks = u & 3;                    // k quarter
    const int r0 = b * NN + qb * 128;

    // Q fragment for this wave's q-tile (pre-scaled by log2e)
    half8_t qf = *reinterpret_cast<const half8_t*>(
        q_ws + (size_t)(r0 + w * 16 + q) * DD + g * 8);

    float m = -3.0e38f, ss = 0.f;
    f32x4 acc0 = {0.f, 0.f, 0.f, 0.f};   // d = 4g+i
    f32x4 acc1 = {0.f, 0.f, 0.f, 0.f};   // d = 16+4g+i

    const int t0 = ks * 64;              // k-tile base within batch (64 tiles = 1024 k)
    // staging sources for wave w (one K tile + one V tile per chunk)
    const half_t* ksrc = k_ws + ((size_t)b * NN + q) * DD + g * 8;  // + tile*16*DD
    const half_t* vsrc = vT3 + (size_t)lane * 8;                    // + gtile*512

    // prologue: stage chunk 0 (wave w stages local tile w)
    {
        half8_t sK = *reinterpret_cast<const half8_t*>(ksrc + (size_t)(t0 + w) * 16 * DD);
        half8_t sV = *reinterpret_cast<const half8_t*>(vsrc + (size_t)(b * 256 + t0 + w) * 512);
        *reinterpret_cast<half8_t*>(&kbuf[0][w][lane * 8]) = sK;
        *reinterpret_cast<half8_t*>(&vbuf[0][w][lane * 8]) = sV;
    }
    __syncthreads();

    for (int ch = 0; ch < NCH; ++ch) {
        const int cb = ch & 1;

        // issue next chunk's loads now (ds_write happens after this chunk's compute)
        half8_t sK, sV;
        if (ch + 1 < NCH) {
            const int lt = t0 + (ch + 1) * 8 + w;
            sK = *reinterpret_cast<const half8_t*>(ksrc + (size_t)lt * 16 * DD);
            sV = *reinterpret_cast<const half8_t*>(vsrc + (size_t)(b * 256 + lt) * 512);
        }

        // compute 8 k-tiles from buf[cb]
#pragma unroll
        for (int t = 0; t < 8; ++t) {
            half8_t kf = *reinterpret_cast<const half8_t*>(&kbuf[cb][t][lane * 8]);
            half8_t vv = *reinterpret_cast<const half8_t*>(&vbuf[cb][t][lane * 8]);

            f32x4 z = {0.f, 0.f, 0.f, 0.f};
            f32x4 s = MFMA_QK(kf, qf, z);

            float tmax = fmaxf(fmaxf(s[0], s[1]), fmaxf(s[2], s[3]));
            if (!__all(tmax <= m + THR2)) {
                float rmax = fmaxf(tmax, __shfl_xor(tmax, 16));
                rmax = fmaxf(rmax, __shfl_xor(rmax, 32));
                float mn = fmaxf(m, rmax);
                float sc = fexp2(m - mn);
                ss *= sc;
                acc0 *= sc;
                acc1 *= sc;
                m = mn;
            }

            float p0 = fexp2(s[0] - m), p1 = fexp2(s[1] - m);
            float p2 = fexp2(s[2] - m), p3 = fexp2(s[3] - m);
            ss += (p0 + p1) + (p2 + p3);

            half2_t pa = pk_f16(p0, p1);
            half2_t pb = pk_f16(p2, p3);
            half4_t pf;
            pf[0] = pa[0]; pf[1] = pa[1]; pf[2] = pb[0]; pf[3] = pb[1];

            half4_t va0 = __builtin_shufflevector(vv, vv, 0, 1, 2, 3);
            half4_t va1 = __builtin_shufflevector(vv, vv, 4, 5, 6, 7);

            acc0 = MFMA_PV(va0, pf, acc0);
            acc1 = MFMA_PV(va1, pf, acc1);
        }

        // write next chunk into the other buffer, then one barrier
        if (ch + 1 < NCH) {
            *reinterpret_cast<half8_t*>(&kbuf[cb ^ 1][w][lane * 8]) = sK;
            *reinterpret_cast<half8_t*>(&vbuf[cb ^ 1][w][lane * 8]) = sV;
        }
        __syncthreads();
    }

    // fold lane-local ss to row sum
    ss += __shfl_xor(ss, 16);
    ss += __shfl_xor(ss, 32);

    // write partials: pm/ps per row; pO[(ks*NROW + r)*32 + d]
    if (lane < 16) {
        pm[(size_t)ks * NROW + r0 + w * 16 + lane] = m;
        ps[(size_t)ks * NROW + r0 + w * 16 + lane] = ss;
    }
    {
        const int r = r0 + w * 16 + q;
        float* po = pO + ((size_t)ks * NROW + r) * 32;
        *reinterpret_cast<f32x4*>(po + g * 4) = acc0;
        *reinterpret_cast<f32x4*>(po + 16 + g * 4) = acc1;
    }
}

// ---------------- Kernel 3: combine + output projection ----------------
// grid 256 blocks (b*64+qb) x 512 threads. Block = 64 q-rows. (R15-verified)
__global__ __launch_bounds__(512) void attn_combine(
    const float* __restrict__ pm, const float* __restrict__ ps,
    const float* __restrict__ pO,
    const float* __restrict__ x, const float* __restrict__ Wo,
    const float* __restrict__ bo, const float* __restrict__ gamma,
    float* __restrict__ out)
{
    __shared__ half_t feat_h[64 * 40];    // 5 KB
    __shared__ half_t woT[256 * 40];      // 20 KB Wo^T f16: woT[c*40+d]

    const int tid = threadIdx.x;
    const int b = blockIdx.x >> 6, qb = blockIdx.x & 63;
    const int q0 = qb * 64;
    const int r0 = b * NN + q0;

    // stage Wo^T as f16
#pragma unroll
    for (int it = 0; it < 16; ++it) {
        int idx = tid + it * 512;
        int c = idx & 255, d = idx >> 8;
        woT[c * 40 + d] = (half_t)Wo[d * CC + c];
    }

    // exact softmax merge of 4 k-split partials: thread -> (r = tid>>3, d4 = (tid&7)*4)
    {
        const int r = tid >> 3, d4 = (tid & 7) * 4;
        const int gr = r0 + r;
        float mv[4];
        float M = -3.0e38f;
#pragma unroll
        for (int k = 0; k < KSPLIT; ++k) {
            mv[k] = pm[(size_t)k * NROW + gr];
            M = fmaxf(M, mv[k]);
        }
        float S = 0.f;
        f32x4 f = {0.f, 0.f, 0.f, 0.f};
#pragma unroll
        for (int k = 0; k < KSPLIT; ++k) {
            float wgt = fexp2(mv[k] - M);
            S += ps[(size_t)k * NROW + gr] * wgt;
            f32x4 p = *reinterpret_cast<const f32x4*>(pO + ((size_t)k * NROW + gr) * 32 + d4);
            f += p * wgt;
        }
        float inv = 1.0f / S;
#pragma unroll
        for (int i = 0; i < 4; ++i) feat_h[r * 40 + d4 + i] = (half_t)(f[i] * inv);
    }
    __syncthreads();

    // MFMA epilogue: O[r][c] = gamma*(feat@Wo + bo) + x  (validated structure)
    const int w = tid >> 6, lane = tid & 63;
    const int q = lane & 15, g = lane >> 4;
    const float gam = gamma[0];
#pragma unroll
    for (int j = 0; j < 2; ++j) {
        const int ct = w * 2 + j;
        half8_t kfe = *reinterpret_cast<const half8_t*>(&woT[(ct * 16 + q) * 40 + g * 8]);
        float4 bb4 = *reinterpret_cast<const float4*>(bo + ct * 16 + g * 4);
#pragma unroll
        for (int rt = 0; rt < 4; ++rt) {
            half8_t qfe = *reinterpret_cast<const half8_t*>(&feat_h[(rt * 16 + q) * 40 + g * 8]);
            f32x4 z = {0.f, 0.f, 0.f, 0.f};
            f32x4 o = MFMA_QK(kfe, qfe, z);
            const size_t base = ((size_t)b * NN + q0 + rt * 16 + q) * CC + ct * 16 + g * 4;
            float4 xv = *reinterpret_cast<const float4*>(x + base);
            float4 ov;
            ov.x = gam * (o[0] + bb4.x) + xv.x;
            ov.y = gam * (o[1] + bb4.y) + xv.y;
            ov.z = gam * (o[2] + bb4.z) + xv.z;
            ov.w = gam * (o[3] + bb4.w) + xv.w;
            *reinterpret_cast<float4*>(out + base) = ov;
        }
    }
}

// ---------------- launch ----------------
extern "C" void kernel_launch(void* const* d_in, const int* in_sizes, int n_in,
                              void* d_out, int out_size, void* d_ws, size_t ws_size,
                              hipStream_t stream) {
    const float* x  = (const float*)d_in[0];
    const float* Wk = (const float*)d_in[1];
    const float* bk = (const float*)d_in[2];
    const float* Wq = (const float*)d_in[3];
    const float* bq = (const float*)d_in[4];
    const float* Wv = (const float*)d_in[5];
    const float* bv = (const float*)d_in[6];
    const float* Wo = (const float*)d_in[7];
    const float* bo = (const float*)d_in[8];
    const float* gamma = (const float*)d_in[9];
    float* out = (float*)d_out;

    half_t* k_ws = (half_t*)d_ws;
    half_t* q_ws = k_ws + (size_t)BB * NN * DD;
    half_t* vT3  = q_ws + (size_t)BB * NN * DD;
    float*  pm   = (float*)(vT3 + (size_t)BB * NN * DD);
    float*  ps   = pm + (size_t)KSPLIT * NROW;
    float*  pO   = ps + (size_t)KSPLIT * NROW;

    proj_kernel<<<256, 512, 0, stream>>>(x, Wk, bk, Wq, bq, Wv, bv, k_ws, q_ws, vT3);
    attn_partial<<<512, 512, 0, stream>>>(k_ws, q_ws, vT3, pm, ps, pO);
    attn_combine<<<256, 512, 0, stream>>>(pm, ps, pO, x, Wo, bo, gamma, out);
}